// Round 7
// baseline (1592.761 us; speedup 1.0000x reference)
//
#include <hip/hip_runtime.h>
#include <hip/hip_bf16.h>
#include <math.h>

// LightingSpeechShield — 4-layer conv+banded-attn speech mask net.
// B=1024, F=257, C=32. Inputs fp32, OUTPUT fp32 (reference returns float32;
// rounds 0-5 failed solely because we stored bf16 into the fp32 d_out).
// fp32 compute, fp32 ping-pong intermediates.
// ws: bufA (BF*32 f32) | bufB (BF*32 f32) | partials (5120*64 f32) | stats (256 f32)
// total ~68.7 MB (proven writable: sub#0/4/5 executed cleanly with this layout).

#define BB 1024
#define FF 257
#define BF (BB*FF)         // 263168
#define TILE 64
#define NT 5               // ceil(257/64)
#define NBLK (BB*NT)       // 5120
#define NLAYER 4

__device__ __forceinline__ float gelu_exact(float x){
    return 0.5f*x*(1.0f+erff(x*0.70710678118654752f));
}

__global__ __launch_bounds__(256) void k_zero(float* __restrict__ stats){
    stats[threadIdx.x]=0.0f;   // 256 = NLAYER*64
}

// ---------------- input projection: h = x(B,F,18) @ in_w(18,32) + in_b ----------------
__global__ __launch_bounds__(256) void k_inproj(const float* __restrict__ x,
        const float* __restrict__ in_w, const float* __restrict__ in_b,
        float* __restrict__ h)
{
    __shared__ float w[18*32];
    __shared__ float bias[32];
    __shared__ float xs[TILE*18];
    int b = blockIdx.x / NT, t = blockIdx.x % NT;
    int t0 = t*TILE;
    int tid = threadIdx.x;
    for (int i=tid;i<18*32;i+=256) w[i]=in_w[i];
    if (tid<32) bias[tid]=in_b[tid];
    int nv = min(TILE, FF-t0);
    for (int i=tid;i<nv*18;i+=256) xs[i]=x[(b*FF+t0)*18+i];
    __syncthreads();
    int co=tid&31, rq=tid>>5;
    for (int k=0;k<8;k++){
        int r=rq*8+k;
        if (r<nv){
            float acc=bias[co];
            #pragma unroll
            for(int i=0;i<18;i++) acc=fmaf(xs[r*18+i], w[i*32+co], acc);
            h[(b*FF+t0+r)*32+co]=acc;
        }
    }
}

// ---------------- conv (recompute) -> BN partial sums only ----------------
__global__ __launch_bounds__(256) void k_convstats(const float* __restrict__ h,
        const float* __restrict__ conv_w, int layer, float* __restrict__ partials)
{
    __shared__ float w[3*32*32];
    __shared__ float hs[66*32];      // rows: f = t0-1 .. t0+64
    __shared__ float ps[8][32];
    __shared__ float pq[8][32];
    int b=blockIdx.x/NT, t=blockIdx.x%NT, t0=t*TILE, tid=threadIdx.x;
    for (int i=tid;i<3072;i+=256) w[i]=conv_w[layer*3072+i];
    for (int i=tid;i<66*32;i+=256){
        int r=i>>5, cc=i&31, f=t0-1+r;
        hs[i] = (f>=0 && f<FF) ? h[(b*FF+f)*32+cc] : 0.f;
    }
    __syncthreads();
    int co=tid&31, rq=tid>>5;
    float ssum=0.f, ssq=0.f;
    for (int k=0;k<8;k++){
        int r=rq*8+k, f=t0+r;
        if (f<FF){
            float acc=0.f;
            #pragma unroll
            for(int wi=0;wi<3;wi++)
                #pragma unroll
                for(int ci=0;ci<32;ci++)
                    acc=fmaf(hs[(r+wi)*32+ci], w[(wi*32+ci)*32+co], acc);
            ssum+=acc; ssq+=acc*acc;
        }
    }
    ps[rq][co]=ssum; pq[rq][co]=ssq;
    __syncthreads();
    if (tid<32){
        float s=0.f;
        #pragma unroll
        for(int q=0;q<8;q++) s+=ps[q][tid];
        partials[blockIdx.x*64+tid]=s;
    } else if (tid<64){
        int cc=tid-32;
        float s=0.f;
        #pragma unroll
        for(int q=0;q<8;q++) s+=pq[q][cc];
        partials[blockIdx.x*64+tid]=s;
    }
}

// ---------------- reduce partials -> stats[64] (sum | sumsq) ----------------
__global__ __launch_bounds__(256) void k_reduce(const float* __restrict__ partials,
        float* __restrict__ stats)
{
    __shared__ float sm[4][64];
    int tid=threadIdx.x, col=tid&63, rq=tid>>6;
    int r0=blockIdx.x*80;               // 64 blocks * 80 rows = 5120
    float s=0.f;
    for (int k=rq;k<80;k+=4) s += partials[(r0+k)*64+col];
    sm[rq][col]=s;
    __syncthreads();
    if (tid<64){
        float v=sm[0][tid]+sm[1][tid]+sm[2][tid]+sm[3][tid];
        atomicAdd(&stats[tid], v);
    }
}

// ---------------- fused layer: conv+BN+gelu + banded attn + residual + LN ----------------
__global__ __launch_bounds__(256) void k_layer(const float* __restrict__ h,
        float* __restrict__ hn, const float* __restrict__ stats,
        const float* __restrict__ conv_w, const float* __restrict__ bn_g,
        const float* __restrict__ bn_b, const float* __restrict__ qkv_w,
        const float* __restrict__ proj_w, const float* __restrict__ proj_b,
        const float* __restrict__ ln_g, const float* __restrict__ ln_b, int layer)
{
    __shared__ float hs[67*32];                       // rows f = t0-1 .. t0+65
    __shared__ union { float qw[3072]; float ys[64*33]; } u;   // qw dead after phase A
    __shared__ union { float cw[3072]; float pw[32*32]; } w2;  // cw dead after phase B
    __shared__ float qs[66*33];  // becomes attention output in-place
    __shared__ float ks[66*33];
    __shared__ float vs[66*33];
    __shared__ float pb[32], sc[32], sh[32], lg[32], lb[32];
    __shared__ float lm[64], lrs[64];

    int b=blockIdx.x/NT, t=blockIdx.x%NT, t0=t*TILE, tid=threadIdx.x;
    for (int i=tid;i<3072;i+=256){
        u.qw[i]=qkv_w[layer*3072+i];
        w2.cw[i]=conv_w[layer*3072+i];
    }
    if (tid<32){
        pb[tid]=proj_b[layer*32+tid];
        lg[tid]=ln_g[layer*32+tid];
        lb[tid]=ln_b[layer*32+tid];
        float mu  = stats[tid]*(1.0f/(float)BF);
        float var = stats[32+tid]*(1.0f/(float)BF) - mu*mu;   // biased
        float rs  = rsqrtf(fmaxf(var,0.f)+1e-5f);
        float g   = bn_g[layer*32+tid];
        sc[tid]=g*rs;
        sh[tid]=bn_b[layer*32+tid] - mu*g*rs;
    }
    for (int i=tid;i<67*32;i+=256){
        int r=i>>5, cc=i&31, f=t0-1+r;
        hs[i] = (f>=0 && f<FF) ? h[(b*FF+f)*32+cc] : 0.f;
    }
    __syncthreads();
    // phase A: qkv for f = t0+idx, idx 0..65 (hs rows 1..66)
    for (int i=tid;i<66*96;i+=256){
        int r=i/96, cc=i%96;
        float acc=0.f;
        #pragma unroll
        for (int ci=0;ci<32;ci++) acc=fmaf(hs[(r+1)*32+ci], u.qw[ci*96+cc], acc);
        if (cc<32)      qs[r*33+cc]      =acc;
        else if (cc<64) ks[r*33+(cc-32)] =acc;
        else            vs[r*33+(cc-64)] =acc;
    }
    __syncthreads();
    // phase B: conv + BN-scale + gelu -> u.ys (qw dead)
    int co=tid&31, rq=tid>>5;
    for (int k=0;k<8;k++){
        int r=rq*8+k, f=t0+r;
        if (f<FF){
            float acc=0.f;
            #pragma unroll
            for(int wi=0;wi<3;wi++)
                #pragma unroll
                for(int ci=0;ci<32;ci++)
                    acc=fmaf(hs[(r+wi)*32+ci], w2.cw[(wi*32+ci)*32+co], acc);
            u.ys[r*33+co]=gelu_exact(fmaf(acc, sc[co], sh[co]));
        }
    }
    __syncthreads();
    // phase C: banded attention (qs in-place) + load pw over cw
    for (int i=tid;i<1024;i+=256) w2.pw[i]=proj_w[layer*1024+i];
    {
        int r=tid>>2, hh=tid&3, f=t0+r;
        if (f<FF){
            int base=hh*8;
            float q8[8];
            #pragma unroll
            for(int d=0;d<8;d++) q8[d]=qs[r*33+base+d];
            float s0, s1=-1e30f, s2=-1e30f;
            {
                float acc=0.f;
                #pragma unroll
                for(int d=0;d<8;d++) acc=fmaf(q8[d], ks[r*33+base+d], acc);
                s0=acc*0.35355339059327373f;
            }
            if (f+1<FF){
                float acc=0.f;
                #pragma unroll
                for(int d=0;d<8;d++) acc=fmaf(q8[d], ks[(r+1)*33+base+d], acc);
                s1=acc*0.35355339059327373f;
            }
            if (f+2<FF){
                float acc=0.f;
                #pragma unroll
                for(int d=0;d<8;d++) acc=fmaf(q8[d], ks[(r+2)*33+base+d], acc);
                s2=acc*0.35355339059327373f;
            }
            float mx=fmaxf(s0,fmaxf(s1,s2));
            float e0=expf(s0-mx);
            float e1=(f+1<FF)?expf(s1-mx):0.f;
            float e2=(f+2<FF)?expf(s2-mx):0.f;
            float inv=1.0f/(e0+e1+e2);
            #pragma unroll
            for(int d=0;d<8;d++){
                float o=e0*vs[r*33+base+d];
                if (f+1<FF) o=fmaf(e1, vs[(r+1)*33+base+d], o);
                if (f+2<FF) o=fmaf(e2, vs[(r+2)*33+base+d], o);
                qs[r*33+base+d]=o*inv;
            }
        }
    }
    __syncthreads();
    // phase D: proj + residual into ys
    for (int k=0;k<8;k++){
        int r=rq*8+k, f=t0+r;
        if (f<FF){
            float acc=pb[co];
            #pragma unroll
            for(int ci=0;ci<32;ci++) acc=fmaf(qs[r*33+ci], w2.pw[ci*32+co], acc);
            u.ys[r*33+co]+=acc;
        }
    }
    __syncthreads();
    // phase E: LayerNorm stats per row
    if (tid<64){
        int r=tid, f=t0+r;
        if (f<FF){
            float s=0.f;
            #pragma unroll
            for(int c2=0;c2<32;c2++) s+=u.ys[r*33+c2];
            float m=s*(1.0f/32.0f);
            float v=0.f;
            #pragma unroll
            for(int c2=0;c2<32;c2++){ float d=u.ys[r*33+c2]-m; v=fmaf(d,d,v); }
            lm[r]=m; lrs[r]=rsqrtf(fmaxf(v,0.f)*(1.0f/32.0f)+1e-5f);
        }
    }
    __syncthreads();
    // phase F: normalized fp32 write
    for (int k=0;k<8;k++){
        int r=rq*8+k, f=t0+r;
        if (f<FF){
            float y=u.ys[r*33+co];
            hn[(b*FF+f)*32+co]=(y-lm[r])*lrs[r]*lg[co]+lb[co];
        }
    }
}

// ---------------- head: sigmoid(gelu(h@h1+b1)@h2+b2) -> FP32 out ----------------
__global__ __launch_bounds__(256) void k_head(const float* __restrict__ h,
        const float* __restrict__ h1_w, const float* __restrict__ h1_b,
        const float* __restrict__ h2_w, const float* __restrict__ h2_b,
        float* __restrict__ out)
{
    __shared__ float hs[256*33];
    __shared__ float w1[32*16];
    __shared__ float b1[16];
    __shared__ float w2[16];
    __shared__ float b2s[1];
    int tid=threadIdx.x;
    int r0=blockIdx.x*256;          // BF == 1028*256 exactly
    for(int i=tid;i<256*32;i+=256){ int r=i>>5, cc=i&31; hs[r*33+cc]=h[r0*32+i]; }
    for(int i=tid;i<512;i+=256) w1[i]=h1_w[i];
    if (tid<16){ b1[tid]=h1_b[tid]; w2[tid]=h2_w[tid]; }
    if (tid==16) b2s[0]=h2_b[0];
    __syncthreads();
    float acc2=b2s[0];
    #pragma unroll
    for(int j=0;j<16;j++){
        float acc=b1[j];
        #pragma unroll
        for(int ci=0;ci<32;ci++) acc=fmaf(hs[tid*33+ci], w1[ci*16+j], acc);
        acc2=fmaf(gelu_exact(acc), w2[j], acc2);
    }
    out[r0+tid]=1.0f/(1.0f+expf(-acc2));
}

extern "C" void kernel_launch(void* const* d_in, const int* in_sizes, int n_in,
                              void* d_out, int out_size, void* d_ws, size_t ws_size,
                              hipStream_t stream)
{
    const float* x     =(const float*)d_in[0];
    const float* in_w  =(const float*)d_in[1];
    const float* in_b  =(const float*)d_in[2];
    const float* conv_w=(const float*)d_in[3];
    const float* bn_g  =(const float*)d_in[4];
    const float* bn_b  =(const float*)d_in[5];
    const float* qkv_w =(const float*)d_in[6];
    const float* proj_w=(const float*)d_in[7];
    const float* proj_b=(const float*)d_in[8];
    const float* ln_g  =(const float*)d_in[9];
    const float* ln_b  =(const float*)d_in[10];
    const float* h1_w  =(const float*)d_in[11];
    const float* h1_b  =(const float*)d_in[12];
    const float* h2_w  =(const float*)d_in[13];
    const float* h2_b  =(const float*)d_in[14];

    float* bufA     = (float*)d_ws;
    float* bufB     = bufA + (size_t)BF*32;
    float* partials = bufB + (size_t)BF*32;
    float* stats    = partials + (size_t)NBLK*64;   // 4 layers * 64 floats

    k_zero<<<1,256,0,stream>>>(stats);
    k_inproj<<<NBLK,256,0,stream>>>(x,in_w,in_b,bufA);
    for (int l=0;l<NLAYER;l++){
        float* cur = (l&1)? bufB : bufA;
        float* nxt = (l&1)? bufA : bufB;
        k_convstats<<<NBLK,256,0,stream>>>(cur, conv_w, l, partials);
        k_reduce<<<64,256,0,stream>>>(partials, stats + l*64);
        k_layer<<<NBLK,256,0,stream>>>(cur, nxt, stats+l*64, conv_w, bn_g, bn_b,
                                       qkv_w, proj_w, proj_b, ln_g, ln_b, l);
    }
    k_head<<<1028,256,0,stream>>>(bufA, h1_w,h1_b,h2_w,h2_b, (float*)d_out);
}